// Round 1
// baseline (141.290 us; speedup 1.0000x reference)
//
#include <hip/hip_runtime.h>

#define NB 8
#define NA 120000
#define NK 80
#define NM 32

#define ALPHA_F 0.25f
#define EPS_F 1e-4f

// ws layout: float acc[24] at offset 0 (cls_sum[8], reg_sum[8], num_pos[8]),
// int8 status[NB*NA] at offset 256.
#define ACC_CLS 0
#define ACC_REG 8
#define ACC_NP  16

#define BLK_A 256
#define BPB_A ((NA + BLK_A - 1) / BLK_A)   // 469 blocks per batch item

#define BLK_B 256
#define BPB_B 256                          // blocks per batch item for focal

__global__ void init_acc(float* __restrict__ acc) {
    if (threadIdx.x < 24) acc[threadIdx.x] = 0.0f;
}

__global__ __launch_bounds__(BLK_A) void assign_kernel(
    const float* __restrict__ anchors,      // [NA,4]
    const float* __restrict__ regressions,  // [NB,NA,4]
    const float* __restrict__ annotations,  // [NB,NM,5]
    signed char* __restrict__ status,       // [NB,NA]
    float* __restrict__ acc)
{
    const int b = blockIdx.x / BPB_A;
    const int a = (blockIdx.x % BPB_A) * BLK_A + threadIdx.x;

    __shared__ float ann[NM * 5];
    if (threadIdx.x < NM * 5) ann[threadIdx.x] = annotations[b * NM * 5 + threadIdx.x];
    __syncthreads();

    float reg_local = 0.0f;
    float pos_local = 0.0f;

    if (a < NA) {
        const float4 av = ((const float4*)anchors)[a];
        const float aw = av.z - av.x;
        const float ah = av.w - av.y;
        const float aarea = aw * ah;

        float best = -1e30f;
        int bm = 0;
        #pragma unroll
        for (int m = 0; m < NM; ++m) {
            const float bx1 = ann[m * 5 + 0];
            const float by1 = ann[m * 5 + 1];
            const float bx2 = ann[m * 5 + 2];
            const float by2 = ann[m * 5 + 3];
            const float lbl = ann[m * 5 + 4];
            float iw = fmaxf(fminf(av.z, bx2) - fmaxf(av.x, bx1), 0.0f);
            float ih = fmaxf(fminf(av.w, by2) - fmaxf(av.y, by1), 0.0f);
            const float inter = iw * ih;
            const float ua = fmaxf(aarea + (bx2 - bx1) * (by2 - by1) - inter, 1e-8f);
            float iou = inter / ua;
            if (lbl == -1.0f) iou = -1.0f;             // padding mask
            if (iou > best) { best = iou; bm = m; }     // strict > == first-occurrence argmax
        }

        int st;
        if (best >= 0.5f) {
            st = (int)ann[bm * 5 + 4];
            // regression loss for positive anchor
            const float bx1 = ann[bm * 5 + 0];
            const float by1 = ann[bm * 5 + 1];
            const float bx2 = ann[bm * 5 + 2];
            const float by2 = ann[bm * 5 + 3];
            const float gw0 = bx2 - bx1;
            const float gh0 = by2 - by1;
            const float gcx = bx1 + 0.5f * gw0;
            const float gcy = by1 + 0.5f * gh0;
            const float gw = fmaxf(gw0, 1.0f);
            const float gh = fmaxf(gh0, 1.0f);
            const float acx = av.x + 0.5f * aw;
            const float acy = av.y + 0.5f * ah;
            float rt0 = ((gcx - acx) / aw) / 0.1f;
            float rt1 = ((gcy - acy) / ah) / 0.1f;
            float rt2 = logf(gw / aw) / 0.2f;
            float rt3 = logf(gh / ah) / 0.2f;
            const float4 rg = ((const float4*)regressions)[b * NA + a];
            float s = 0.0f;
            float d;
            d = fabsf(rt0 - rg.x); s += (d <= 1.0f / 9.0f) ? 4.5f * d * d : d - 0.5f / 9.0f;
            d = fabsf(rt1 - rg.y); s += (d <= 1.0f / 9.0f) ? 4.5f * d * d : d - 0.5f / 9.0f;
            d = fabsf(rt2 - rg.z); s += (d <= 1.0f / 9.0f) ? 4.5f * d * d : d - 0.5f / 9.0f;
            d = fabsf(rt3 - rg.w); s += (d <= 1.0f / 9.0f) ? 4.5f * d * d : d - 0.5f / 9.0f;
            reg_local = s;
            pos_local = 1.0f;
        } else {
            st = (best < 0.4f) ? -2 : -1;
        }
        status[b * NA + a] = (signed char)st;
    }

    // block reduction of (reg_local, pos_local)
    #pragma unroll
    for (int o = 32; o > 0; o >>= 1) {
        reg_local += __shfl_down(reg_local, o, 64);
        pos_local += __shfl_down(pos_local, o, 64);
    }
    __shared__ float wr[BLK_A / 64], wp[BLK_A / 64];
    const int lane = threadIdx.x & 63;
    const int wid = threadIdx.x >> 6;
    if (lane == 0) { wr[wid] = reg_local; wp[wid] = pos_local; }
    __syncthreads();
    if (threadIdx.x == 0) {
        float rsum = 0.0f, psum = 0.0f;
        #pragma unroll
        for (int i = 0; i < BLK_A / 64; ++i) { rsum += wr[i]; psum += wp[i]; }
        atomicAdd(&acc[ACC_REG + b], rsum);
        atomicAdd(&acc[ACC_NP + b], psum);
    }
}

__device__ __forceinline__ float clampc(float x) {
    return fminf(fmaxf(x, EPS_F), 1.0f - EPS_F);
}
__device__ __forceinline__ float negl(float c) {
    // t == 0: (1-alpha) * c^2 * (-log(1-c))
    return (1.0f - ALPHA_F) * c * c * (-__logf(1.0f - c));
}
__device__ __forceinline__ float posl(float c) {
    // t == 1: alpha * (1-c)^2 * (-log(c))
    const float omc = 1.0f - c;
    return ALPHA_F * omc * omc * (-__logf(c));
}

__global__ __launch_bounds__(BLK_B) void focal_kernel(
    const float* __restrict__ cls,          // [NB,NA,NK]
    const signed char* __restrict__ status, // [NB,NA]
    float* __restrict__ acc)
{
    const int b = blockIdx.x / BPB_B;
    const int blk = blockIdx.x % BPB_B;
    const float4* base = (const float4*)(cls + (size_t)b * NA * NK);
    const signed char* stb = status + b * NA;
    const int n4 = NA * NK / 4;             // 2,400,000 float4 per batch item

    float sum = 0.0f;
    for (int i = blk * BLK_B + threadIdx.x; i < n4; i += BPB_B * BLK_B) {
        const float4 v = base[i];
        const int a = i / 20;               // 80/4 = 20 float4 per anchor
        const int k0 = (i - a * 20) * 4;
        const int st = stb[a];
        if (st != -1) {                     // -1 = ignore
            const float c0 = clampc(v.x);
            const float c1 = clampc(v.y);
            const float c2 = clampc(v.z);
            const float c3 = clampc(v.w);
            float l = negl(c0) + negl(c1) + negl(c2) + negl(c3);
            if (st >= k0 && st < k0 + 4) {  // positive anchor, assigned class in window
                const float c = (st == k0) ? c0 : (st == k0 + 1) ? c1 : (st == k0 + 2) ? c2 : c3;
                l += posl(c) - negl(c);
            }
            sum += l;
        }
    }

    #pragma unroll
    for (int o = 32; o > 0; o >>= 1) sum += __shfl_down(sum, o, 64);
    __shared__ float ws[BLK_B / 64];
    const int lane = threadIdx.x & 63;
    const int wid = threadIdx.x >> 6;
    if (lane == 0) ws[wid] = sum;
    __syncthreads();
    if (threadIdx.x == 0) {
        float s = 0.0f;
        #pragma unroll
        for (int i = 0; i < BLK_B / 64; ++i) s += ws[i];
        atomicAdd(&acc[ACC_CLS + b], s);
    }
}

__global__ void finalize_kernel(const float* __restrict__ acc, float* __restrict__ out) {
    if (threadIdx.x == 0) {
        float cs = 0.0f, rs = 0.0f;
        #pragma unroll
        for (int b = 0; b < NB; ++b) {
            const float np = acc[ACC_NP + b];
            cs += acc[ACC_CLS + b] / fmaxf(np, 1.0f);
            rs += (np > 0.0f) ? acc[ACC_REG + b] / fmaxf(np * 4.0f, 1.0f) : 0.0f;
        }
        out[0] = cs / (float)NB;
        out[1] = rs / (float)NB;
    }
}

extern "C" void kernel_launch(void* const* d_in, const int* in_sizes, int n_in,
                              void* d_out, int out_size, void* d_ws, size_t ws_size,
                              hipStream_t stream) {
    const float* cls = (const float*)d_in[0];   // [NB,NA,NK]
    const float* reg = (const float*)d_in[1];   // [NB,NA,4]
    const float* anc = (const float*)d_in[2];   // [1,NA,4]
    const float* ann = (const float*)d_in[3];   // [NB,NM,5]

    float* acc = (float*)d_ws;
    signed char* status = (signed char*)d_ws + 256;
    float* out = (float*)d_out;

    init_acc<<<1, 64, 0, stream>>>(acc);
    assign_kernel<<<NB * BPB_A, BLK_A, 0, stream>>>(anc, reg, ann, status, acc);
    focal_kernel<<<NB * BPB_B, BLK_B, 0, stream>>>(cls, status, acc);
    finalize_kernel<<<1, 64, 0, stream>>>(acc, out);
}